// Round 4
// baseline (737.277 us; speedup 1.0000x reference)
//
#include <hip/hip_runtime.h>
#include <hip/hip_bf16.h>

#define NN 100000
#define NE 1600000
#define NH 4
#define NC 32
#define DD 128
#define NG 64
#define NIN 7

#define BSH 9                       // bucket = dst >> 9 (512 nodes/bucket)
#define NBUK ((NN + 511) >> BSH)    // 196
#define SEGCAP 9600                 // CSR per-bucket stride (mean 8704, +10 sigma)
#define CAPE (SEGCAP - 512)         // 9088 staged edges/bucket max -> segN <= SEGCAP always
#define CSRN (NBUK * SEGCAP)        // 1881600 csr entries
#define NBBIN ((NE + 4095)/4096)    // 391 binning blocks

typedef __hip_bfloat16 bf16;
typedef __attribute__((ext_vector_type(8))) short short8;
typedef __attribute__((ext_vector_type(4))) float f32x4;
typedef __attribute__((ext_vector_type(2))) float f32x2;

__device__ __forceinline__ float b2f(const bf16 v){ return __bfloat162float(v); }

// flag-steered input load: f32 ? fp32 tensor : bf16 tensor
__device__ __forceinline__ float in_ld(const void* p, size_t i, int f32){
  return f32 ? ((const float*)p)[i] : b2f(((const bf16*)p)[i]);
}

__device__ __forceinline__ unsigned int bfbits(float v){
  bf16 b = __float2bfloat16(v);
  return (unsigned int)(*(unsigned short*)&b);
}

// block-level dtype sniff of first 512 words of x (call with >=64 threads)
__device__ __forceinline__ int sniff_f32(const unsigned int* __restrict__ xb, int* s_f32){
  if (threadIdx.x < 64){
    int t = threadIdx.x;
    int pl = 0;
    for (int j = t; j < 512; j += 64){
      float v = __uint_as_float(xb[j]);
      float a = fabsf(v);
      if (v == v && a < 1e6f && a > 1e-10f) pl++;
    }
    #pragma unroll
    for (int off = 32; off > 0; off >>= 1) pl += __shfl_down(pl, off);
    if (t == 0) *s_f32 = (pl >= 384) ? 1 : 0;   // >=75% plausible => fp32
  }
  __syncthreads();
  return *s_f32;
}

// ---------------- Pass 1: bin 4096 edges/block by dst-bucket (+ prep tail blocks) ----------------
// tail blocks: NBBIN..NBBIN+2 = WT transpose (self-sniffed flag); NBBIN+3 = global flag writer
__global__ __launch_bounds__(512) void k_bucket_fwd();  // fwd decl dummy (unused)

__global__ __launch_bounds__(256) void k_bin(const int* __restrict__ src, const int* __restrict__ dst,
                                             int* __restrict__ bcur, int2* __restrict__ gstag,
                                             const void* __restrict__ Ws, bf16* __restrict__ WT,
                                             const unsigned int* __restrict__ xb, int* __restrict__ flag){
  if (blockIdx.x >= NBBIN){
    __shared__ int s_f32;
    int f32 = sniff_f32(xb, &s_f32);
    int l = blockIdx.x - NBBIN;   // 0..3
    if (l == 3){
      if (threadIdx.x == 0) *flag = f32;   // consumed by later launches (stream-ordered)
      return;
    }
    // WT[n][k] = W[k][n], bf16 — 3 layers, one block each
    for (int idx = threadIdx.x; idx < DD*DD; idx += 256){
      int n = idx >> 7, k = idx & 127;
      WT[(size_t)l*DD*DD + idx] = __float2bfloat16(in_ld(Ws, (size_t)l*DD*DD + (size_t)k*DD + n, f32));
    }
    return;
  }
  __shared__ int cnt[NBUK], pref[NBUK+1], place[NBUK], gbase[NBUK];
  __shared__ int2 pairs[4096];   // 32 KB
  int tid = threadIdx.x;
  for (int b = tid; b < NBUK; b += 256){ cnt[b]=0; place[b]=0; }
  __syncthreads();
  int e0 = blockIdx.x*4096;
  int s[16], d[16];
  #pragma unroll
  for (int i=0;i<16;i++){
    int e = e0 + i*256 + tid;
    s[i] = 0; d[i] = -1;
    if (e < NE){
      unsigned int us = (unsigned int)src[e]; if (us >= NN) us = 0;   // firewall
      unsigned int ud = (unsigned int)dst[e]; if (ud >= NN) ud = 0;   // firewall
      s[i] = (int)us; d[i] = (int)ud;
      atomicAdd(&cnt[ud>>BSH], 1);
    }
  }
  __syncthreads();
  if (tid == 0){
    int run = 0;
    for (int b=0;b<NBUK;b++){ pref[b] = run; run += cnt[b]; }
    pref[NBUK] = run;
  }
  __syncthreads();
  for (int b = tid; b < NBUK; b += 256){
    if (cnt[b] > 0) gbase[b] = b*CAPE + atomicAdd(&bcur[b], cnt[b]);   // bcur is bucket-relative
  }
  __syncthreads();
  #pragma unroll
  for (int i=0;i<16;i++){
    if (d[i] >= 0){
      int b = d[i]>>BSH;
      int lp = atomicAdd(&place[b],1);
      pairs[pref[b]+lp] = make_int2(s[i], d[i]);
    }
  }
  __syncthreads();
  int tot = pref[NBUK];
  for (int j = tid; j < tot; j += 256){
    int2 pr = pairs[j];
    int b = pr.y>>BSH;
    int gidx = gbase[b] + (j - pref[b]);
    // firewall: stay inside bucket b's staging strip
    if (gidx >= b*CAPE && gidx < (b+1)*CAPE) gstag[gidx] = pr;
  }
}

// ---------------- Pass 2: per-bucket count + scan + CSR segment in LDS (512 threads) ----------------
__global__ __launch_bounds__(512) void k_bucket(const int2* __restrict__ gstag,
                                                const int* __restrict__ bcur,
                                                int* __restrict__ csr,
                                                int* __restrict__ offs, int* __restrict__ oend){
  __shared__ int seg[SEGCAP];    // 37.5 KB
  __shared__ int lcnt[512];
  __shared__ int loff[512];
  __shared__ int s_segN;
  int b = blockIdx.x, tid = threadIdx.x;   // tid 0..511
  int nstart = b << BSH;
  int nend = min(nstart + 512, NN);
  int nloc = nend - nstart;
  int base = b * SEGCAP;
  int stbase = b * CAPE;
  int ecnt = bcur[b];                      // bucket-relative count
  ecnt = max(0, min(ecnt, CAPE));
  // counts: 1 (self loop) per valid node
  lcnt[tid] = (tid < nloc) ? 1 : 0;
  __syncthreads();
  for (int j = tid; j < ecnt; j += 512){
    int2 pr = gstag[stbase + j];
    int ln = pr.y - nstart;
    if (ln < 0 || ln >= nloc) ln = 0;   // firewall
    atomicAdd(&lcnt[ln], 1);
  }
  __syncthreads();
  int own = lcnt[tid];
  // inclusive Hillis-Steele scan over 512 in loff
  loff[tid] = own;
  __syncthreads();
  for (int off=1; off<512; off<<=1){
    int a = (tid >= off) ? loff[tid-off] : 0;
    __syncthreads();
    loff[tid] += a;
    __syncthreads();
  }
  int incl = loff[tid];
  loff[tid] = incl - own;        // exclusive (own slot only; cross-reads after sync)
  if (tid == 511) s_segN = incl;
  __syncthreads();
  int segN = s_segN;
  if (segN > SEGCAP) segN = SEGCAP;     // structurally impossible; firewall
  if (tid < nloc){
    offs[nstart + tid] = base + loff[tid];
    oend[nstart + tid] = base + loff[tid] + own;
    int p = loff[tid];
    if (p < SEGCAP) seg[p] = nstart + tid;   // self loop in slot 0
    lcnt[tid] = 1;                           // reuse as fill cursor
  }
  __syncthreads();
  for (int j = tid; j < ecnt; j += 512){
    int2 pr = gstag[stbase + j];
    int ln = pr.y - nstart;
    if (ln < 0 || ln >= nloc) ln = 0;
    int p = atomicAdd(&lcnt[ln], 1);
    int idx = loff[ln] + p;
    if (idx >= 0 && idx < SEGCAP) seg[idx] = pr.x;
  }
  __syncthreads();
  for (int j = tid; j < segN; j += 512) csr[base + j] = seg[j];
}

// ---------------- layer-0 projection (IN_DIM=7) + alpha; 8 nodes / 256 threads ----------------
__device__ __forceinline__ void alpha_red(float acc, float was, float wad, int d, int n,
                                          float* __restrict__ asrc, float* __restrict__ adst){
  float ps = acc*was, pd = acc*wad;
  #pragma unroll
  for (int off=16; off>0; off>>=1){
    ps += __shfl_down(ps, off, 32);
    pd += __shfl_down(pd, off, 32);
  }
  if ((d & 31) == 0){
    asrc[n*NH + (d>>5)] = ps;
    adst[n*NH + (d>>5)] = pd;
  }
}

__global__ __launch_bounds__(256) void k_gemm0(const void* __restrict__ x, const void* __restrict__ W,
    const void* __restrict__ aws, const void* __restrict__ awd,
    bf16* __restrict__ hproj,
    float* __restrict__ asrc, float* __restrict__ adst, const int* __restrict__ flag){
  int f32 = *flag;
  __shared__ float xr[8][NIN];
  int t = threadIdx.x;
  int d = t & 127;
  int nb = (t >> 7) * 4;              // node sub-group 0 or 4
  int n0 = blockIdx.x*8;              // NN % 8 == 0
  if (t < 8*NIN) xr[t/NIN][t%NIN] = in_ld(x, (size_t)n0*NIN + t, f32);
  __syncthreads();
  float a0=0,a1=0,a2=0,a3=0;
  #pragma unroll
  for (int k=0;k<NIN;k++){
    float w = in_ld(W, (size_t)k*DD + d, f32);
    a0 += xr[nb+0][k]*w; a1 += xr[nb+1][k]*w; a2 += xr[nb+2][k]*w; a3 += xr[nb+3][k]*w;
  }
  hproj[(size_t)(n0+nb+0)*DD+d]=__float2bfloat16(a0);
  hproj[(size_t)(n0+nb+1)*DD+d]=__float2bfloat16(a1);
  hproj[(size_t)(n0+nb+2)*DD+d]=__float2bfloat16(a2);
  hproj[(size_t)(n0+nb+3)*DD+d]=__float2bfloat16(a3);
  float was = in_ld(aws, d, f32), wad = in_ld(awd, d, f32);
  alpha_red(a0, was, wad, d, n0+nb+0, asrc, adst);
  alpha_red(a1, was, wad, d, n0+nb+1, asrc, adst);
  alpha_red(a2, was, wad, d, n0+nb+2, asrc, adst);
  alpha_red(a3, was, wad, d, n0+nb+3, asrc, adst);
}

// ---------------- layers 1..3: MFMA GEMM, 128 rows/block, B from global (WT is L1-hot) --------
// sA rows padded to 136 elements (272 B): b128 frag reads land 2 lanes/bank (free).
#define LDA 136
#define GRPB 128

__global__ __launch_bounds__(256) void k_gemm_mfma(
    const bf16* __restrict__ resid,           // bf16 residual stream in ws
    const bf16* __restrict__ WT, size_t wtoff,
    const void* __restrict__ aws, const void* __restrict__ awd, size_t aoff,
    bf16* __restrict__ hproj,
    float* __restrict__ asrc, float* __restrict__ adst,
    const int* __restrict__ flag)
{
  __shared__ bf16 sA[GRPB*LDA];    // 34.8 KB -> 4 blocks/CU
  int f32 = *flag;
  int t = threadIdx.x;
  int n0 = blockIdx.x*GRPB;

  // stage A: bf16 residual rows n0..n0+127 -> sA (pure uint4 copy; row = 16 uint4)
  {
    const uint4* av = (const uint4*)resid;
    #pragma unroll
    for (int i=0;i<8;i++){
      int u4 = t + 256*i;          // 0..2047
      int row = u4 >> 4, c = u4 & 15;
      int gr = n0 + row;
      uint4 v = make_uint4(0,0,0,0);
      if (gr < NN) v = av[(size_t)gr*16 + c];
      *(uint4*)(&sA[row*LDA + c*8]) = v;
    }
  }
  __syncthreads();

  int wv = t >> 6, lane = t & 63;
  int m = lane & 15, kq = lane >> 4;      // kq = 0..3
  const bf16* WB = WT + wtoff;            // [n][k] transposed weights, 32 KB, L1-resident

  f32x4 acc[2][8];
  #pragma unroll
  for (int rg=0; rg<2; rg++)
    #pragma unroll
    for (int nt=0; nt<8; nt++) acc[rg][nt] = (f32x4){0.f,0.f,0.f,0.f};

  #pragma unroll
  for (int ks=0; ks<4; ks++){
    short8 af0 = *(const short8*)(&sA[(wv*32 +  0 + m)*LDA + ks*32 + kq*8]);
    short8 af1 = *(const short8*)(&sA[(wv*32 + 16 + m)*LDA + ks*32 + kq*8]);
    #pragma unroll
    for (int nt=0; nt<8; nt++){
      short8 bf = *(const short8*)(WB + (size_t)(nt*16 + m)*DD + ks*32 + kq*8);
      acc[0][nt] = __builtin_amdgcn_mfma_f32_16x16x32_bf16(af0, bf, acc[0][nt], 0, 0, 0);
      acc[1][nt] = __builtin_amdgcn_mfma_f32_16x16x32_bf16(af1, bf, acc[1][nt], 0, 0, 0);
    }
  }

  // store C -> hproj (bf16). C/D layout: col = lane&15, row = kq*4 + reg
  #pragma unroll
  for (int rg=0; rg<2; rg++){
    #pragma unroll
    for (int reg=0; reg<4; reg++){
      int gr = n0 + wv*32 + rg*16 + kq*4 + reg;
      if (gr < NN){
        bf16* dst = hproj + (size_t)gr*DD + m;
        #pragma unroll
        for (int nt=0; nt<8; nt++)
          dst[nt*16] = __float2bfloat16(acc[rg][nt][reg]);
      }
    }
  }

  // fused alpha: per-lane a-vector values at col = nt*16 + m
  float avs[8], avd[8];
  #pragma unroll
  for (int nt=0; nt<8; nt++){
    avs[nt] = in_ld(aws, aoff + nt*16 + m, f32);
    avd[nt] = in_ld(awd, aoff + nt*16 + m, f32);
  }
  #pragma unroll
  for (int rg=0; rg<2; rg++){
    #pragma unroll
    for (int h=0; h<4; h++){
      #pragma unroll
      for (int reg=0; reg<4; reg++){
        float ps = acc[rg][2*h][reg]*avs[2*h] + acc[rg][2*h+1][reg]*avs[2*h+1];
        float pd = acc[rg][2*h][reg]*avd[2*h] + acc[rg][2*h+1][reg]*avd[2*h+1];
        #pragma unroll
        for (int off=1; off<16; off<<=1){
          ps += __shfl_xor(ps, off);
          pd += __shfl_xor(pd, off);
        }
        if (m == 0){
          int gr = n0 + wv*32 + rg*16 + kq*4 + reg;
          if (gr < NN){
            asrc[gr*NH + h] = ps;
            adst[gr*NH + h] = pd;
          }
        }
      }
    }
  }
}

// ---------------- attention aggregation + LN + ELU + residual ----------------
__device__ __forceinline__ float4 edge_e(const float4 as, const float4 ad){
  float4 l, e;
  l.x = as.x + ad.x; l.y = as.y + ad.y; l.z = as.z + ad.z; l.w = as.w + ad.w;
  l.x = l.x > 0.f ? l.x : 0.2f*l.x;
  l.y = l.y > 0.f ? l.y : 0.2f*l.y;
  l.z = l.z > 0.f ? l.z : 0.2f*l.z;
  l.w = l.w > 0.f ? l.w : 0.2f*l.w;
  l.x = fminf(l.x, 30.f); l.y = fminf(l.y, 30.f);   // firewall: true logits <= ~10
  l.z = fminf(l.z, 30.f); l.w = fminf(l.w, 30.f);
  e.x = __expf(l.x); e.y = __expf(l.y); e.z = __expf(l.z); e.w = __expf(l.w);
  return e;
}

__device__ __forceinline__ float2 hp_ld2(const void* hp, int s, int lane){
  unsigned int hv = ((const unsigned int*)hp)[(size_t)s*64 + lane];
  return make_float2(__uint_as_float(hv << 16), __uint_as_float(hv & 0xFFFF0000u));
}

__device__ __forceinline__ void fma_row(const uint4 hv, const float al,
                                        f32x2& a0, f32x2& a1, f32x2& a2, f32x2& a3){
  f32x2 v0 = {__uint_as_float(hv.x << 16), __uint_as_float(hv.x & 0xFFFF0000u)};
  f32x2 v1 = {__uint_as_float(hv.y << 16), __uint_as_float(hv.y & 0xFFFF0000u)};
  f32x2 v2 = {__uint_as_float(hv.z << 16), __uint_as_float(hv.z & 0xFFFF0000u)};
  f32x2 v3 = {__uint_as_float(hv.w << 16), __uint_as_float(hv.w & 0xFFFF0000u)};
  a0 += v0 * al;
  a1 += v1 * al;
  a2 += v2 * al;
  a3 += v3 * al;
}

// One node per wave. Gather is quad-split: lanes 16g..16g+15 read row t+4u+g,
// lane ql owns the 16B chunk at byte ql*16 -> full 256B row per 16-lane group,
// 1KB per wave-load instruction. U = rows in flight per main-loop iter.
template<int U>
__global__ __launch_bounds__(256) void k_agg(const bf16* __restrict__ hproj,
    const float* __restrict__ asrc, const float* __restrict__ adst,
    const int* __restrict__ offs, const int* __restrict__ oend, const int* __restrict__ csr,
    bf16* __restrict__ resid,
    const void* __restrict__ bias, size_t boff,
    const void* __restrict__ lng, const void* __restrict__ lnb, size_t lnoff,
    const int* __restrict__ flag, const int first)
{
  __shared__ float s_al[4][256];
  __shared__ int   s_off[4][64];
  int f32 = *flag;
  int wid = threadIdx.x >> 6, lane = threadIdx.x & 63;
  int n = blockIdx.x*4 + wid;        // NN % 4 == 0
  int beg = offs[n];
  int end = oend[n];
  beg = max(0, min(beg, CSRN));
  end = max(beg, min(end, CSRN));
  int deg = min(end - beg, 1024);    // firewall; true max deg ~50
  const float4 ad = ((const float4*)adst)[n];
  int head = lane >> 4;
  const char* hpB = (const char*)hproj;
  float2 acc;

  if (deg <= 64){
    // ---- setup: per-lane neighbor, alpha numerator, softmax z ----
    float4 e = make_float4(0,0,0,0);
    if (lane < deg){
      unsigned int us = (unsigned int)csr[beg+lane];
      if (us >= NN) us = 0;          // firewall
      s_off[wid][lane] = (int)(us << 8);   // row byte offset (256 B/row)
      float4 as = ((const float4*)asrc)[us];
      e = edge_e(as, ad);
    }
    float4 zs = e;
    #pragma unroll
    for (int off=32; off>0; off>>=1){
      zs.x += __shfl_down(zs.x, off);
      zs.y += __shfl_down(zs.y, off);
      zs.z += __shfl_down(zs.z, off);
      zs.w += __shfl_down(zs.w, off);
    }
    float4 invz;
    invz.x = 1.f/(__shfl(zs.x,0)+1e-16f);
    invz.y = 1.f/(__shfl(zs.y,0)+1e-16f);
    invz.z = 1.f/(__shfl(zs.z,0)+1e-16f);
    invz.w = 1.f/(__shfl(zs.w,0)+1e-16f);
    if (lane < deg){
      s_al[wid][lane*4+0] = e.x*invz.x;
      s_al[wid][lane*4+1] = e.y*invz.y;
      s_al[wid][lane*4+2] = e.z*invz.z;
      s_al[wid][lane*4+3] = e.w*invz.w;
    }
    __threadfence_block();

    // ---- gather: quad-split; U rows per main iter (U/4 loads in flight/lane) ----
    int qg = lane >> 4;        // quad group = row slot within a 4-row pack
    int ql = lane & 15;        // position within row
    int hq = ql >> 2;          // head of owned channels (8ql mod 32 in {0,8,16,24})
    int qbyte = ql << 4;       // byte offset of owned 16B chunk within row
    f32x2 a0 = {0.f,0.f}, a1 = {0.f,0.f}, a2 = {0.f,0.f}, a3 = {0.f,0.f};
    int t = 0;
    for (; t+U <= deg; t += U){
      uint4 h[U/4];
      #pragma unroll
      for (int u=0; u<U/4; u++){
        int j = t + 4*u + qg;
        unsigned int off = (unsigned int)s_off[wid][j] + qbyte;
        h[u] = *(const uint4*)(hpB + off);
      }
      #pragma unroll
      for (int u=0; u<U/4; u++){
        int j = t + 4*u + qg;
        float al = s_al[wid][j*4 + hq];
        fma_row(h[u], al, a0, a1, a2, a3);
      }
    }
    for (; t+4 <= deg; t += 4){
      int j = t + qg;
      unsigned int off = (unsigned int)s_off[wid][j] + qbyte;
      const uint4 hv = *(const uint4*)(hpB + off);
      float al = s_al[wid][j*4 + hq];
      fma_row(hv, al, a0, a1, a2, a3);
    }
    if (t < deg){
      int j = t + qg;
      if (j < deg){
        unsigned int off = (unsigned int)s_off[wid][j] + qbyte;
        const uint4 hv = *(const uint4*)(hpB + off);
        float al = s_al[wid][j*4 + hq];
        fma_row(hv, al, a0, a1, a2, a3);
      }
    }

    // ---- reduce across the 4 quad groups ----
    #pragma unroll
    for (int off = 16; off < 64; off <<= 1){
      a0.x += __shfl_xor(a0.x, off); a0.y += __shfl_xor(a0.y, off);
      a1.x += __shfl_xor(a1.x, off); a1.y += __shfl_xor(a1.y, off);
      a2.x += __shfl_xor(a2.x, off); a2.y += __shfl_xor(a2.y, off);
      a3.x += __shfl_xor(a3.x, off); a3.y += __shfl_xor(a3.y, off);
    }
    // redistribute to epilogue layout (lane l owns channels 2l, 2l+1) via s_al reuse
    __threadfence_block();   // all lanes past their s_al reads (wave-synchronous)
    if (qg == 0){
      float* red = &s_al[wid][0];
      red[ql*8+0] = a0.x; red[ql*8+1] = a0.y;
      red[ql*8+2] = a1.x; red[ql*8+3] = a1.y;
      red[ql*8+4] = a2.x; red[ql*8+5] = a2.y;
      red[ql*8+6] = a3.x; red[ql*8+7] = a3.y;
    }
    __threadfence_block();
    acc = make_float2(s_al[wid][2*lane], s_al[wid][2*lane+1]);
  } else {
    // general path (cold)
    f32x2 ac0 = {0.f,0.f};
    float4 zs = make_float4(0,0,0,0);
    for (int j=lane; j<deg; j+=64){
      unsigned int us = (unsigned int)csr[beg+j];
      if (us >= NN) us = 0;
      float4 as = ((const float4*)asrc)[us];
      float4 e = edge_e(as, ad);
      zs.x+=e.x; zs.y+=e.y; zs.z+=e.z; zs.w+=e.w;
    }
    #pragma unroll
    for (int off=32; off>0; off>>=1){
      zs.x += __shfl_down(zs.x, off);
      zs.y += __shfl_down(zs.y, off);
      zs.z += __shfl_down(zs.z, off);
      zs.w += __shfl_down(zs.w, off);
    }
    float4 invz;
    invz.x = 1.f/(__shfl(zs.x,0)+1e-16f);
    invz.y = 1.f/(__shfl(zs.y,0)+1e-16f);
    invz.z = 1.f/(__shfl(zs.z,0)+1e-16f);
    invz.w = 1.f/(__shfl(zs.w,0)+1e-16f);
    int nch = (deg+63)>>6;
    for (int c2=0;c2<nch;c2++){
      int base = c2<<6, j = base+lane;
      int sreg = 0;
      __threadfence_block();
      if (j < deg){
        unsigned int us = (unsigned int)csr[beg+j];
        if (us >= NN) us = 0;
        sreg = (int)us;
        float4 as = ((const float4*)asrc)[us];
        float4 e = edge_e(as, ad);
        s_al[wid][lane*4+0]=e.x*invz.x;
        s_al[wid][lane*4+1]=e.y*invz.y;
        s_al[wid][lane*4+2]=e.z*invz.z;
        s_al[wid][lane*4+3]=e.w*invz.w;
      }
      __threadfence_block();
      int cnt = min(64, deg-base);
      for (int t2=0;t2<cnt;t2++){
        int s = __shfl(sreg, t2);
        float a = s_al[wid][t2*4+head];
        float2 hv = hp_ld2(hproj, s, lane);
        ac0.x += hv.x*a;
        ac0.y += hv.y*a;
      }
    }
    acc = make_float2(ac0.x, ac0.y);
  }

  // epilogue: bias + layernorm + elu + residual (residual stream is bf16 in ws)
  float vx = acc.x + in_ld(bias, boff + 2*lane,   f32);
  float vy = acc.y + in_ld(bias, boff + 2*lane+1, f32);
  float s1 = vx+vy, s2 = vx*vx+vy*vy;
  #pragma unroll
  for (int off=32; off>0; off>>=1){
    s1 += __shfl_down(s1, off);
    s2 += __shfl_down(s2, off);
  }
  float mean = __shfl(s1,0) * (1.f/DD);
  float msq  = __shfl(s2,0) * (1.f/DD);
  float var  = fmaxf(msq - mean*mean, 0.f);
  float r = rsqrtf(var + 1e-5f);
  float yx = (vx-mean)*r*in_ld(lng, lnoff+2*lane,   f32) + in_ld(lnb, lnoff+2*lane,   f32);
  float yy = (vy-mean)*r*in_ld(lng, lnoff+2*lane+1, f32) + in_ld(lnb, lnoff+2*lane+1, f32);
  yx = yx>0.f ? yx : expm1f(yx);
  yy = yy>0.f ? yy : expm1f(yy);
  float2 res;
  if (first){
    res = make_float2(yx, yy);
  } else {
    unsigned int pu = ((const unsigned int*)resid)[(size_t)n*64 + lane];
    res = make_float2(__uint_as_float(pu << 16) + yx,
                      __uint_as_float(pu & 0xFFFF0000u) + yy);
  }
  unsigned int pk = bfbits(res.x) | (bfbits(res.y) << 16);
  ((unsigned int*)resid)[(size_t)n*64 + lane] = pk;
}

// ---------------- pooling + fused finalize (last block divides & writes graph embedding) ----
__global__ __launch_bounds__(128) void k_pool(const bf16* __restrict__ resid, void* __restrict__ dout,
    const int* __restrict__ batch, float* __restrict__ gsum, int* __restrict__ gcnt,
    int* __restrict__ ctr, const int* __restrict__ flag){
  __shared__ int sb[64];
  __shared__ int s_last;
  int f32 = *flag;
  int d = threadIdx.x;
  int n0 = blockIdx.x*64;
  int cnt = min(64, NN - n0);
  if (d < cnt){
    unsigned int b = (unsigned int)batch[n0 + d];
    if (b >= NG) b = 0;            // firewall
    sb[d] = (int)b;
  }
  __syncthreads();
  float local = 0.f;
  int cur = sb[0];
  for (int i=0;i<cnt;i++){
    int b = sb[i];
    if (b != cur){
      atomicAdd(&gsum[cur*DD + d], local);
      local = 0.f; cur = b;
    }
    size_t idx = (size_t)(n0+i)*DD + d;
    float v = b2f(resid[idx]);
    if (f32) ((float*)dout)[idx] = v;
    else     ((bf16*)dout)[idx] = resid[idx];
    local += v;
  }
  atomicAdd(&gsum[cur*DD + d], local);
  if (d == 0){
    int lc = 0; int c2 = sb[0];
    for (int i=0;i<cnt;i++){
      int b = sb[i];
      if (b != c2){ atomicAdd(&gcnt[c2], lc); lc = 0; c2 = b; }
      lc++;
    }
    atomicAdd(&gcnt[c2], lc);
  }
  // finalize: last block to finish divides and writes graph embedding
  __threadfence();
  if (d == 0){
    int done = atomicAdd(ctr, 1);
    s_last = (done == (int)gridDim.x - 1) ? 1 : 0;
  }
  __syncthreads();
  if (s_last){
    __threadfence();
    for (int i = d; i < NG*DD; i += 128){
      float sv = __hip_atomic_load(&gsum[i], __ATOMIC_RELAXED, __HIP_MEMORY_SCOPE_AGENT);
      int   cv = __hip_atomic_load(&gcnt[i>>7], __ATOMIC_RELAXED, __HIP_MEMORY_SCOPE_AGENT);
      float c = (float)cv;
      if (c < 1.f) c = 1.f;
      float val = sv / c;
      if (f32) ((float*)dout)[(size_t)NN*DD + i] = val;
      else     ((bf16*)dout)[(size_t)NN*DD + i] = __float2bfloat16(val);
    }
  }
}

extern "C" void kernel_launch(void* const* d_in, const int* in_sizes, int n_in,
                              void* d_out, int out_size, void* d_ws, size_t ws_size,
                              hipStream_t stream){
  const void* x      = d_in[0];
  const int*  ei     = (const int*) d_in[1];
  const int*  batch  = (const int*) d_in[2];
  const void* W0     = d_in[3];
  const void* asrc0  = d_in[4];
  const void* adst0  = d_in[5];
  const void* b0     = d_in[6];
  const void* Ws     = d_in[7];
  const void* asrcs  = d_in[8];
  const void* adsts  = d_in[9];
  const void* bs     = d_in[10];
  const void* lng    = d_in[11];
  const void* lnb    = d_in[12];

  const int* srcs = ei;
  const int* dsts = ei + NE;

  uintptr_t p0 = (uintptr_t)d_ws;
  uintptr_t p = p0;
  auto alloc = [&](size_t bytes)->void* {
    void* r = (void*)p; p += (bytes + 255) & ~(size_t)255; return r;
  };
  // zeroed block (one contiguous memset): gsum, gcnt, ctr, bcur
  float* gsum   = (float*)alloc((size_t)NG*DD*4);
  int*   gcnt   = (int*)  alloc(NG*4);
  int*   ctr    = (int*)  alloc(256);
  int*   bcur   = (int*)  alloc((size_t)NBUK*4);        // bucket-relative cursors
  size_t zbytes = (size_t)(p - (uintptr_t)gsum);
  // rest
  int*   csr    = (int*)  alloc((size_t)CSRN*4);        // 7.5 MB fixed-stride CSR
  int*   offs   = (int*)  alloc((size_t)NN*4);
  int*   oend   = (int*)  alloc((size_t)NN*4);
  float* asrc   = (float*)alloc((size_t)NN*NH*4);
  float* adst   = (float*)alloc((size_t)NN*NH*4);
  int*   flag   = (int*)  alloc(256);
  int2*  gstag  = (int2*) alloc((size_t)NBUK*CAPE*8);   // 14.2 MB fixed-stride staging
  bf16*  wt     = (bf16*) alloc((size_t)3*DD*DD*2);     // 96 KB transposed layer weights
  bf16*  hproj  = (bf16*) alloc((size_t)NN*DD*2);       // 25.6 MB
  bf16*  resid  = (bf16*) alloc((size_t)NN*DD*2);       // 25.6 MB residual stream

  hipMemsetAsync(gsum, 0, zbytes, stream);

  k_bin<<<NBBIN + 4, 256, 0, stream>>>(srcs, dsts, bcur, gstag, Ws, wt,
                                       (const unsigned int*)x, flag);
  k_bucket<<<NBUK, 512, 0, stream>>>(gstag, bcur, csr, offs, oend);

  const int GEMM_B = (NN + GRPB - 1)/GRPB;  // 782

  // layer 0
  k_gemm0<<<NN/8, 256, 0, stream>>>(x, W0, asrc0, adst0, hproj, asrc, adst, flag);
  k_agg<8><<<NN/4, 256, 0, stream>>>(hproj, asrc, adst, offs, oend, csr, resid,
                                     b0, 0, lng, lnb, 0, flag, 1);
  // layers 1..3
  for (int l=1; l<4; l++){
    size_t wtoff = (size_t)(l-1)*DD*DD;
    size_t aoff  = (size_t)(l-1)*DD;
    k_gemm_mfma<<<GEMM_B, 256, 0, stream>>>(resid, wt, wtoff,
                                            asrcs, adsts, aoff,
                                            hproj, asrc, adst, flag);
    k_agg<8><<<NN/4, 256, 0, stream>>>(hproj, asrc, adst, offs, oend, csr, resid,
                                       bs, (size_t)(l-1)*DD, lng, lnb, (size_t)l*DD, flag, 0);
  }

  k_pool<<<(NN+63)/64, 128, 0, stream>>>(resid, d_out, batch, gsum, gcnt, ctr, flag);
}

// Round 5
// 615.094 us; speedup vs baseline: 1.1986x; 1.1986x over previous
//
#include <hip/hip_runtime.h>
#include <hip/hip_bf16.h>

#define NN 100000
#define NE 1600000
#define NH 4
#define NC 32
#define DD 128
#define NG 64
#define NIN 7

#define BSH 9                       // bucket = dst >> 9 (512 nodes/bucket)
#define NBUK ((NN + 511) >> BSH)    // 196
#define SEGCAP 9600                 // CSR per-bucket stride (mean 8704, +10 sigma)
#define CAPE (SEGCAP - 512)         // 9088 staged edges/bucket max -> segN <= SEGCAP always
#define CSRN (NBUK * SEGCAP)        // 1881600 csr entries
#define NBBIN ((NE + 4095)/4096)    // 391 binning blocks

typedef __hip_bfloat16 bf16;
typedef __attribute__((ext_vector_type(8))) short short8;
typedef __attribute__((ext_vector_type(4))) float f32x4;
typedef __attribute__((ext_vector_type(2))) float f32x2;

__device__ __forceinline__ float b2f(const bf16 v){ return __bfloat162float(v); }

// flag-steered input load: f32 ? fp32 tensor : bf16 tensor
__device__ __forceinline__ float in_ld(const void* p, size_t i, int f32){
  return f32 ? ((const float*)p)[i] : b2f(((const bf16*)p)[i]);
}

__device__ __forceinline__ unsigned int bfbits(float v){
  bf16 b = __float2bfloat16(v);
  return (unsigned int)(*(unsigned short*)&b);
}

// ---------------- init (+ dtype sniffer in block 0) ----------------
__global__ __launch_bounds__(256) void k_init(float* __restrict__ gsum, int* __restrict__ gcnt,
                                              int* __restrict__ bcur,
                                              const unsigned int* __restrict__ xb, int* __restrict__ flag){
  int i = blockIdx.x*256 + threadIdx.x;
  if (i < NG*DD) gsum[i] = 0.f;
  if (i < NG) gcnt[i] = 0;
  if (i < NBUK) bcur[i] = i * CAPE;          // fixed-stride staging base
  if (blockIdx.x == 0 && threadIdx.x < 64){
    int t = threadIdx.x;
    int pl = 0;
    for (int j = t; j < 512; j += 64){
      float v = __uint_as_float(xb[j]);
      float a = fabsf(v);
      if (v == v && a < 1e6f && a > 1e-10f) pl++;
    }
    #pragma unroll
    for (int off = 32; off > 0; off >>= 1) pl += __shfl_down(pl, off);
    if (t == 0) *flag = (pl >= 384) ? 1 : 0;   // >=75% plausible => fp32
  }
}

// ---------------- Pass 1: bin 4096 edges/block by dst-bucket (+ W-prep tail blocks) ----------------
__global__ __launch_bounds__(256) void k_bin(const int* __restrict__ src, const int* __restrict__ dst,
                                             int* __restrict__ bcur, int2* __restrict__ gstag,
                                             const void* __restrict__ Ws, bf16* __restrict__ WT,
                                             const int* __restrict__ flag){
  if (blockIdx.x >= NBBIN){
    // WT[n][k] = W[k][n], bf16 — 3 layers, one block each
    int l = blockIdx.x - NBBIN;   // 0..2
    int f32 = *flag;              // written by k_init (prior launch, stream-ordered)
    for (int idx = threadIdx.x; idx < DD*DD; idx += 256){
      int n = idx >> 7, k = idx & 127;
      WT[(size_t)l*DD*DD + idx] = __float2bfloat16(in_ld(Ws, (size_t)l*DD*DD + (size_t)k*DD + n, f32));
    }
    return;
  }
  __shared__ int cnt[NBUK], pref[NBUK+1], place[NBUK], gbase[NBUK];
  __shared__ int2 pairs[4096];   // 32 KB
  int tid = threadIdx.x;
  for (int b = tid; b < NBUK; b += 256){ cnt[b]=0; place[b]=0; }
  __syncthreads();
  int e0 = blockIdx.x*4096;
  int s[16], d[16];
  #pragma unroll
  for (int i=0;i<16;i++){
    int e = e0 + i*256 + tid;
    s[i] = 0; d[i] = -1;
    if (e < NE){
      unsigned int us = (unsigned int)src[e]; if (us >= NN) us = 0;   // firewall
      unsigned int ud = (unsigned int)dst[e]; if (ud >= NN) ud = 0;   // firewall
      s[i] = (int)us; d[i] = (int)ud;
      atomicAdd(&cnt[ud>>BSH], 1);
    }
  }
  __syncthreads();
  if (tid == 0){
    int run = 0;
    for (int b=0;b<NBUK;b++){ pref[b] = run; run += cnt[b]; }
    pref[NBUK] = run;
  }
  __syncthreads();
  for (int b = tid; b < NBUK; b += 256){
    if (cnt[b] > 0) gbase[b] = atomicAdd(&bcur[b], cnt[b]);
  }
  __syncthreads();
  #pragma unroll
  for (int i=0;i<16;i++){
    if (d[i] >= 0){
      int b = d[i]>>BSH;
      int lp = atomicAdd(&place[b],1);
      pairs[pref[b]+lp] = make_int2(s[i], d[i]);
    }
  }
  __syncthreads();
  int tot = pref[NBUK];
  for (int j = tid; j < tot; j += 256){
    int2 pr = pairs[j];
    int b = pr.y>>BSH;
    int gidx = gbase[b] + (j - pref[b]);
    // firewall: stay inside bucket b's staging strip
    if (gidx >= b*CAPE && gidx < (b+1)*CAPE) gstag[gidx] = pr;
  }
}

// ---------------- Pass 2: per-bucket count + scan + CSR segment in LDS ----------------
__global__ __launch_bounds__(256) void k_bucket(const int2* __restrict__ gstag,
                                                const int* __restrict__ bcur,
                                                int* __restrict__ csr,
                                                int* __restrict__ offs, int* __restrict__ oend){
  __shared__ int seg[SEGCAP];    // 37.5 KB
  __shared__ int lcnt[512];
  __shared__ int loff[512];
  __shared__ int pscan[256];
  int b = blockIdx.x, tid = threadIdx.x;
  int nstart = b << BSH;
  int nend = min(nstart + 512, NN);
  int nloc = nend - nstart;
  int base = b * SEGCAP;
  int stbase = b * CAPE;
  int ecnt = bcur[b] - stbase;
  ecnt = max(0, min(ecnt, CAPE));
  // counts: 1 (self loop) per valid node
  lcnt[tid]     = (tid < nloc) ? 1 : 0;
  lcnt[tid+256] = (tid+256 < nloc) ? 1 : 0;
  __syncthreads();
  for (int j = tid; j < ecnt; j += 256){
    int2 pr = gstag[stbase + j];
    int ln = pr.y - nstart;
    if (ln < 0 || ln >= nloc) ln = 0;   // firewall
    atomicAdd(&lcnt[ln], 1);
  }
  __syncthreads();
  // scan over 512 via pair-sum + Hillis-Steele on 256
  int c0 = lcnt[2*tid], c1 = lcnt[2*tid+1];
  int pairsum = c0 + c1;
  pscan[tid] = pairsum;
  __syncthreads();
  for (int off=1; off<256; off<<=1){
    int a = (tid >= off) ? pscan[tid-off] : 0;
    __syncthreads();
    pscan[tid] += a;
    __syncthreads();
  }
  int pexcl = pscan[tid] - pairsum;
  loff[2*tid]   = pexcl;
  loff[2*tid+1] = pexcl + c0;
  __syncthreads();
  int segN = pscan[255];
  if (segN > SEGCAP) segN = SEGCAP;     // structurally impossible; firewall
  // write offs/oend, place self loops, reset cursors
  if (tid < nloc){
    offs[nstart + tid] = base + loff[tid];
    oend[nstart + tid] = base + loff[tid] + lcnt[tid];
  }
  if (tid + 256 < nloc){
    offs[nstart + tid + 256] = base + loff[tid+256];
    oend[nstart + tid + 256] = base + loff[tid+256] + lcnt[tid+256];
  }
  __syncthreads();
  if (tid < nloc){ int p = loff[tid]; if (p < SEGCAP) seg[p] = nstart + tid; lcnt[tid] = 1; }
  if (tid + 256 < nloc){ int p = loff[tid+256]; if (p < SEGCAP) seg[p] = nstart + tid + 256; lcnt[tid+256] = 1; }
  __syncthreads();
  for (int j = tid; j < ecnt; j += 256){
    int2 pr = gstag[stbase + j];
    int ln = pr.y - nstart;
    if (ln < 0 || ln >= nloc) ln = 0;
    int p = atomicAdd(&lcnt[ln], 1);
    int idx = loff[ln] + p;
    if (idx >= 0 && idx < SEGCAP) seg[idx] = pr.x;
  }
  __syncthreads();
  for (int j = tid; j < segN; j += 256) csr[base + j] = seg[j];
}

// ---------------- layer-0 projection (IN_DIM=7) + alpha ----------------
__device__ __forceinline__ void alpha_red(float acc, float was, float wad, int d, int n,
                                          float* __restrict__ asrc, float* __restrict__ adst){
  float ps = acc*was, pd = acc*wad;
  #pragma unroll
  for (int off=16; off>0; off>>=1){
    ps += __shfl_down(ps, off, 32);
    pd += __shfl_down(pd, off, 32);
  }
  if ((d & 31) == 0){
    asrc[n*NH + (d>>5)] = ps;
    adst[n*NH + (d>>5)] = pd;
  }
}

__global__ __launch_bounds__(128) void k_gemm0(const void* __restrict__ x, const void* __restrict__ W,
    const void* __restrict__ aws, const void* __restrict__ awd,
    bf16* __restrict__ hproj,
    float* __restrict__ asrc, float* __restrict__ adst, const int* __restrict__ flag){
  int f32 = *flag;
  __shared__ float xr[4][NIN];
  int d = threadIdx.x;
  int n0 = blockIdx.x*4;
  if (d < 4*NIN) xr[d/NIN][d%NIN] = in_ld(x, (size_t)n0*NIN + d, f32);
  __syncthreads();
  float a0=0,a1=0,a2=0,a3=0;
  #pragma unroll
  for (int k=0;k<NIN;k++){
    float w = in_ld(W, (size_t)k*DD + d, f32);
    a0 += xr[0][k]*w; a1 += xr[1][k]*w; a2 += xr[2][k]*w; a3 += xr[3][k]*w;
  }
  hproj[(size_t)(n0+0)*DD+d]=__float2bfloat16(a0);
  hproj[(size_t)(n0+1)*DD+d]=__float2bfloat16(a1);
  hproj[(size_t)(n0+2)*DD+d]=__float2bfloat16(a2);
  hproj[(size_t)(n0+3)*DD+d]=__float2bfloat16(a3);
  float was = in_ld(aws, d, f32), wad = in_ld(awd, d, f32);
  alpha_red(a0, was, wad, d, n0+0, asrc, adst);
  alpha_red(a1, was, wad, d, n0+1, asrc, adst);
  alpha_red(a2, was, wad, d, n0+2, asrc, adst);
  alpha_red(a3, was, wad, d, n0+3, asrc, adst);
}

// ---------------- layers 1..3: MFMA GEMM (64 rows/block) + fused alpha ----------------
// LDS rows padded to 136 elements (272 B): b128 frag reads land 2 lanes/bank (free).
#define LDA 136
#define LDB 136

__global__ __launch_bounds__(256) void k_gemm_mfma(
    const bf16* __restrict__ resid,           // bf16 residual stream in ws
    const bf16* __restrict__ WT, size_t wtoff,
    const void* __restrict__ aws, const void* __restrict__ awd, size_t aoff,
    bf16* __restrict__ hproj,
    float* __restrict__ asrc, float* __restrict__ adst,
    const int* __restrict__ flag)
{
  __shared__ bf16 sA[64*LDA];    // 17.0 KB
  __shared__ bf16 sB[128*LDB];   // 34.0 KB
  int f32 = *flag;
  int t = threadIdx.x;
  int n0 = blockIdx.x*64;

  // stage WT (bf16, [n][k]) -> sB. 128x128 bf16 = 2048 uint4; 16 chunks/row.
  {
    const uint4* srcv = (const uint4*)(WT + wtoff);
    #pragma unroll
    for (int i=0;i<8;i++){
      int u4 = t + 256*i;          // 0..2047
      int row = u4 >> 4, c = u4 & 15;
      *(uint4*)(&sB[row*LDB + c*8]) = srcv[u4];
    }
  }
  // stage A: bf16 residual rows n0..n0+63 -> sA (pure uint4 copy; row = 16 uint4)
  {
    const uint4* av = (const uint4*)resid;
    #pragma unroll
    for (int i=0;i<4;i++){
      int u4 = t + 256*i;          // 0..1023
      int row = u4 >> 4, c = u4 & 15;
      int gr = n0 + row;
      uint4 v = make_uint4(0,0,0,0);
      if (gr < NN) v = av[(size_t)gr*16 + c];
      *(uint4*)(&sA[row*LDA + c*8]) = v;
    }
  }
  __syncthreads();

  int wv = t >> 6, lane = t & 63;
  int m = lane & 15, kq = lane >> 4;      // kq = 0..3
  int rowbase = wv*16;

  f32x4 acc[8];
  #pragma unroll
  for (int nt=0; nt<8; nt++) acc[nt] = (f32x4){0.f,0.f,0.f,0.f};

  #pragma unroll
  for (int ks=0; ks<4; ks++){
    short8 afrag = *(const short8*)(&sA[(rowbase + m)*LDA + ks*32 + kq*8]);
    #pragma unroll
    for (int nt=0; nt<8; nt++){
      short8 bfrag = *(const short8*)(&sB[(nt*16 + m)*LDB + ks*32 + kq*8]);
      acc[nt] = __builtin_amdgcn_mfma_f32_16x16x32_bf16(afrag, bfrag, acc[nt], 0, 0, 0);
    }
  }

  // store C -> hproj (bf16). C/D layout: col = lane&15, row = kq*4 + reg
  #pragma unroll
  for (int reg=0; reg<4; reg++){
    int gr = n0 + rowbase + kq*4 + reg;
    if (gr < NN){
      bf16* dst = hproj + (size_t)gr*DD + m;
      #pragma unroll
      for (int nt=0; nt<8; nt++)
        dst[nt*16] = __float2bfloat16(acc[nt][reg]);
    }
  }

  // fused alpha: per-lane a-vector values at col = nt*16 + m
  float avs[8], avd[8];
  #pragma unroll
  for (int nt=0; nt<8; nt++){
    avs[nt] = in_ld(aws, aoff + nt*16 + m, f32);
    avd[nt] = in_ld(awd, aoff + nt*16 + m, f32);
  }
  #pragma unroll
  for (int h=0; h<4; h++){
    #pragma unroll
    for (int reg=0; reg<4; reg++){
      float ps = acc[2*h][reg]*avs[2*h] + acc[2*h+1][reg]*avs[2*h+1];
      float pd = acc[2*h][reg]*avd[2*h] + acc[2*h+1][reg]*avd[2*h+1];
      #pragma unroll
      for (int off=1; off<16; off<<=1){
        ps += __shfl_xor(ps, off);
        pd += __shfl_xor(pd, off);
      }
      if (m == 0){
        int gr = n0 + rowbase + kq*4 + reg;
        if (gr < NN){
          asrc[gr*NH + h] = ps;
          adst[gr*NH + h] = pd;
        }
      }
    }
  }
}

// ---------------- attention aggregation + LN + ELU + residual ----------------
__device__ __forceinline__ float4 edge_e(const float4 as, const float4 ad){
  float4 l, e;
  l.x = as.x + ad.x; l.y = as.y + ad.y; l.z = as.z + ad.z; l.w = as.w + ad.w;
  l.x = l.x > 0.f ? l.x : 0.2f*l.x;
  l.y = l.y > 0.f ? l.y : 0.2f*l.y;
  l.z = l.z > 0.f ? l.z : 0.2f*l.z;
  l.w = l.w > 0.f ? l.w : 0.2f*l.w;
  l.x = fminf(l.x, 30.f); l.y = fminf(l.y, 30.f);   // firewall: true logits <= ~10
  l.z = fminf(l.z, 30.f); l.w = fminf(l.w, 30.f);
  e.x = __expf(l.x); e.y = __expf(l.y); e.z = __expf(l.z); e.w = __expf(l.w);
  return e;
}

__device__ __forceinline__ float2 hp_ld2(const void* hp, int s, int lane){
  unsigned int hv = ((const unsigned int*)hp)[(size_t)s*64 + lane];
  return make_float2(__uint_as_float(hv << 16), __uint_as_float(hv & 0xFFFF0000u));
}

__device__ __forceinline__ void fma_row(const uint4 hv, const float al,
                                        f32x2& a0, f32x2& a1, f32x2& a2, f32x2& a3){
  f32x2 v0 = {__uint_as_float(hv.x << 16), __uint_as_float(hv.x & 0xFFFF0000u)};
  f32x2 v1 = {__uint_as_float(hv.y << 16), __uint_as_float(hv.y & 0xFFFF0000u)};
  f32x2 v2 = {__uint_as_float(hv.z << 16), __uint_as_float(hv.z & 0xFFFF0000u)};
  f32x2 v3 = {__uint_as_float(hv.w << 16), __uint_as_float(hv.w & 0xFFFF0000u)};
  a0 += v0 * al;
  a1 += v1 * al;
  a2 += v2 * al;
  a3 += v3 * al;
}

// One node per wave. Gather is quad-split: lanes 16g..16g+15 read row t+4u+g,
// lane ql owns the 16B chunk at byte ql*16 -> full 256B row per 16-lane group,
// 1KB per wave-load instruction. U = rows in flight per main-loop iter.
template<int U>
__global__ __launch_bounds__(256) void k_agg(const bf16* __restrict__ hproj,
    const float* __restrict__ asrc, const float* __restrict__ adst,
    const int* __restrict__ offs, const int* __restrict__ oend, const int* __restrict__ csr,
    bf16* __restrict__ resid,
    const void* __restrict__ bias, size_t boff,
    const void* __restrict__ lng, const void* __restrict__ lnb, size_t lnoff,
    const int* __restrict__ flag, const int first)
{
  __shared__ float s_al[4][256];
  __shared__ int   s_off[4][64];
  int f32 = *flag;
  int wid = threadIdx.x >> 6, lane = threadIdx.x & 63;
  int n = blockIdx.x*4 + wid;        // NN % 4 == 0
  int beg = offs[n];
  int end = oend[n];
  beg = max(0, min(beg, CSRN));
  end = max(beg, min(end, CSRN));
  int deg = min(end - beg, 1024);    // firewall; true max deg ~50
  const float4 ad = ((const float4*)adst)[n];
  int head = lane >> 4;
  const char* hpB = (const char*)hproj;
  float2 acc;

  if (deg <= 64){
    // ---- setup: per-lane neighbor, alpha numerator, softmax z ----
    float4 e = make_float4(0,0,0,0);
    if (lane < deg){
      unsigned int us = (unsigned int)csr[beg+lane];
      if (us >= NN) us = 0;          // firewall
      s_off[wid][lane] = (int)(us << 8);   // row byte offset (256 B/row)
      float4 as = ((const float4*)asrc)[us];
      e = edge_e(as, ad);
    }
    float4 zs = e;
    #pragma unroll
    for (int off=32; off>0; off>>=1){
      zs.x += __shfl_down(zs.x, off);
      zs.y += __shfl_down(zs.y, off);
      zs.z += __shfl_down(zs.z, off);
      zs.w += __shfl_down(zs.w, off);
    }
    float4 invz;
    invz.x = 1.f/(__shfl(zs.x,0)+1e-16f);
    invz.y = 1.f/(__shfl(zs.y,0)+1e-16f);
    invz.z = 1.f/(__shfl(zs.z,0)+1e-16f);
    invz.w = 1.f/(__shfl(zs.w,0)+1e-16f);
    if (lane < deg){
      s_al[wid][lane*4+0] = e.x*invz.x;
      s_al[wid][lane*4+1] = e.y*invz.y;
      s_al[wid][lane*4+2] = e.z*invz.z;
      s_al[wid][lane*4+3] = e.w*invz.w;
    }
    __threadfence_block();

    // ---- gather: quad-split; U rows per main iter (U/4 loads in flight/lane) ----
    int qg = lane >> 4;        // quad group = row slot within a 4-row pack
    int ql = lane & 15;        // position within row
    int hq = ql >> 2;          // head of owned channels (8ql mod 32 in {0,8,16,24})
    int qbyte = ql << 4;       // byte offset of owned 16B chunk within row
    f32x2 a0 = {0.f,0.f}, a1 = {0.f,0.f}, a2 = {0.f,0.f}, a3 = {0.f,0.f};
    int t = 0;
    for (; t+U <= deg; t += U){
      uint4 h[U/4];
      #pragma unroll
      for (int u=0; u<U/4; u++){
        int j = t + 4*u + qg;
        unsigned int off = (unsigned int)s_off[wid][j] + qbyte;
        h[u] = *(const uint4*)(hpB + off);
      }
      #pragma unroll
      for (int u=0; u<U/4; u++){
        int j = t + 4*u + qg;
        float al = s_al[wid][j*4 + hq];
        fma_row(h[u], al, a0, a1, a2, a3);
      }
    }
    for (; t+4 <= deg; t += 4){
      int j = t + qg;
      unsigned int off = (unsigned int)s_off[wid][j] + qbyte;
      const uint4 hv = *(const uint4*)(hpB + off);
      float al = s_al[wid][j*4 + hq];
      fma_row(hv, al, a0, a1, a2, a3);
    }
    if (t < deg){
      int j = t + qg;
      if (j < deg){
        unsigned int off = (unsigned int)s_off[wid][j] + qbyte;
        const uint4 hv = *(const uint4*)(hpB + off);
        float al = s_al[wid][j*4 + hq];
        fma_row(hv, al, a0, a1, a2, a3);
      }
    }

    // ---- reduce across the 4 quad groups ----
    #pragma unroll
    for (int off = 16; off < 64; off <<= 1){
      a0.x += __shfl_xor(a0.x, off); a0.y += __shfl_xor(a0.y, off);
      a1.x += __shfl_xor(a1.x, off); a1.y += __shfl_xor(a1.y, off);
      a2.x += __shfl_xor(a2.x, off); a2.y += __shfl_xor(a2.y, off);
      a3.x += __shfl_xor(a3.x, off); a3.y += __shfl_xor(a3.y, off);
    }
    // redistribute to epilogue layout (lane l owns channels 2l, 2l+1) via s_al reuse
    __threadfence_block();   // all lanes past their s_al reads (wave-synchronous)
    if (qg == 0){
      float* red = &s_al[wid][0];
      red[ql*8+0] = a0.x; red[ql*8+1] = a0.y;
      red[ql*8+2] = a1.x; red[ql*8+3] = a1.y;
      red[ql*8+4] = a2.x; red[ql*8+5] = a2.y;
      red[ql*8+6] = a3.x; red[ql*8+7] = a3.y;
    }
    __threadfence_block();
    acc = make_float2(s_al[wid][2*lane], s_al[wid][2*lane+1]);
  } else {
    // general path (cold)
    f32x2 ac0 = {0.f,0.f};
    float4 zs = make_float4(0,0,0,0);
    for (int j=lane; j<deg; j+=64){
      unsigned int us = (unsigned int)csr[beg+j];
      if (us >= NN) us = 0;
      float4 as = ((const float4*)asrc)[us];
      float4 e = edge_e(as, ad);
      zs.x+=e.x; zs.y+=e.y; zs.z+=e.z; zs.w+=e.w;
    }
    #pragma unroll
    for (int off=32; off>0; off>>=1){
      zs.x += __shfl_down(zs.x, off);
      zs.y += __shfl_down(zs.y, off);
      zs.z += __shfl_down(zs.z, off);
      zs.w += __shfl_down(zs.w, off);
    }
    float4 invz;
    invz.x = 1.f/(__shfl(zs.x,0)+1e-16f);
    invz.y = 1.f/(__shfl(zs.y,0)+1e-16f);
    invz.z = 1.f/(__shfl(zs.z,0)+1e-16f);
    invz.w = 1.f/(__shfl(zs.w,0)+1e-16f);
    int nch = (deg+63)>>6;
    for (int c2=0;c2<nch;c2++){
      int base = c2<<6, j = base+lane;
      int sreg = 0;
      __threadfence_block();
      if (j < deg){
        unsigned int us = (unsigned int)csr[beg+j];
        if (us >= NN) us = 0;
        sreg = (int)us;
        float4 as = ((const float4*)asrc)[us];
        float4 e = edge_e(as, ad);
        s_al[wid][lane*4+0]=e.x*invz.x;
        s_al[wid][lane*4+1]=e.y*invz.y;
        s_al[wid][lane*4+2]=e.z*invz.z;
        s_al[wid][lane*4+3]=e.w*invz.w;
      }
      __threadfence_block();
      int cnt = min(64, deg-base);
      for (int t2=0;t2<cnt;t2++){
        int s = __shfl(sreg, t2);
        float a = s_al[wid][t2*4+head];
        float2 hv = hp_ld2(hproj, s, lane);
        ac0.x += hv.x*a;
        ac0.y += hv.y*a;
      }
    }
    acc = make_float2(ac0.x, ac0.y);
  }

  // epilogue: bias + layernorm + elu + residual (residual stream is bf16 in ws)
  float vx = acc.x + in_ld(bias, boff + 2*lane,   f32);
  float vy = acc.y + in_ld(bias, boff + 2*lane+1, f32);
  float s1 = vx+vy, s2 = vx*vx+vy*vy;
  #pragma unroll
  for (int off=32; off>0; off>>=1){
    s1 += __shfl_down(s1, off);
    s2 += __shfl_down(s2, off);
  }
  float mean = __shfl(s1,0) * (1.f/DD);
  float msq  = __shfl(s2,0) * (1.f/DD);
  float var  = fmaxf(msq - mean*mean, 0.f);
  float r = rsqrtf(var + 1e-5f);
  float yx = (vx-mean)*r*in_ld(lng, lnoff+2*lane,   f32) + in_ld(lnb, lnoff+2*lane,   f32);
  float yy = (vy-mean)*r*in_ld(lng, lnoff+2*lane+1, f32) + in_ld(lnb, lnoff+2*lane+1, f32);
  yx = yx>0.f ? yx : expm1f(yx);
  yy = yy>0.f ? yy : expm1f(yy);
  float2 res;
  if (first){
    res = make_float2(yx, yy);
  } else {
    unsigned int pu = ((const unsigned int*)resid)[(size_t)n*64 + lane];
    res = make_float2(__uint_as_float(pu << 16) + yx,
                      __uint_as_float(pu & 0xFFFF0000u) + yy);
  }
  unsigned int pk = bfbits(res.x) | (bfbits(res.y) << 16);
  ((unsigned int*)resid)[(size_t)n*64 + lane] = pk;
}

// ---------------- pooling: parallel + vectorized (batch is sorted; <=2 graphs per 64-row block) ----
// 256 threads = 16 row-slots x 16 chunk-lanes. Thread owns 8 channels (16B) of its row.
__global__ __launch_bounds__(256) void k_pool(const bf16* __restrict__ resid, void* __restrict__ dout,
    const int* __restrict__ batch, float* __restrict__ gsum, int* __restrict__ gcnt,
    const int* __restrict__ flag){
  __shared__ int sb[64];
  __shared__ float s_sum[2][DD];
  __shared__ int s_cnt[2];
  int f32 = *flag;
  int t = threadIdx.x;
  int s = t >> 4, ql = t & 15;
  int n0 = blockIdx.x*64;
  int cnt = min(64, NN - n0);
  if (t < 64){
    int bi = 0;
    if (t < cnt){
      unsigned int b = (unsigned int)batch[n0 + t];
      if (b >= NG) b = 0;            // firewall
      bi = (int)b;
    }
    sb[t] = bi;
  }
  ((float*)s_sum)[t] = 0.f;          // 256 threads zero 2*128 cells
  if (t < 2) s_cnt[t] = 0;
  __syncthreads();
  int g0 = sb[0];
  int g1 = sb[cnt-1];
  // counts (sorted batch -> only g0/g1 expected; firewall otherwise)
  if (t < cnt){
    int b = sb[t];
    if (b == g0) atomicAdd(&s_cnt[0], 1);
    else if (b == g1) atomicAdd(&s_cnt[1], 1);
    else atomicAdd(&gcnt[b], 1);
  }
  float acc0[8] = {0,0,0,0,0,0,0,0};
  float acc1[8] = {0,0,0,0,0,0,0,0};
  const uint4* rv = (const uint4*)resid;
  #pragma unroll
  for (int k=0;k<4;k++){
    int r = k*16 + s;
    if (r < cnt){
      int n = n0 + r;
      uint4 hv = rv[(size_t)n*16 + ql];
      float v[8];
      v[0]=__uint_as_float(hv.x<<16); v[1]=__uint_as_float(hv.x&0xFFFF0000u);
      v[2]=__uint_as_float(hv.y<<16); v[3]=__uint_as_float(hv.y&0xFFFF0000u);
      v[4]=__uint_as_float(hv.z<<16); v[5]=__uint_as_float(hv.z&0xFFFF0000u);
      v[6]=__uint_as_float(hv.w<<16); v[7]=__uint_as_float(hv.w&0xFFFF0000u);
      if (f32){
        float4* dp = (float4*)((char*)dout + (size_t)n*512 + ql*32);
        dp[0] = make_float4(v[0],v[1],v[2],v[3]);
        dp[1] = make_float4(v[4],v[5],v[6],v[7]);
      } else {
        *(uint4*)((char*)dout + (size_t)n*256 + ql*16) = hv;
      }
      int b = sb[r];
      if (b == g0){
        #pragma unroll
        for (int i=0;i<8;i++) acc0[i] += v[i];
      } else if (b == g1){
        #pragma unroll
        for (int i=0;i<8;i++) acc1[i] += v[i];
      } else {
        #pragma unroll
        for (int i=0;i<8;i++) atomicAdd(&gsum[b*DD + ql*8 + i], v[i]);  // firewall
      }
    }
  }
  // LDS reduce across the 16 row-slots
  int c0 = ql*8;
  int twog = (g1 != g0);
  #pragma unroll
  for (int i=0;i<8;i++){
    atomicAdd(&s_sum[0][c0+i], acc0[i]);
    if (twog) atomicAdd(&s_sum[1][c0+i], acc1[i]);
  }
  __syncthreads();
  if (t < DD){
    atomicAdd(&gsum[g0*DD + t], s_sum[0][t]);
  } else if (twog && t < 2*DD){
    atomicAdd(&gsum[g1*DD + (t-DD)], s_sum[1][t-DD]);
  }
  if (t == 0){
    atomicAdd(&gcnt[g0], s_cnt[0]);
    if (twog) atomicAdd(&gcnt[g1], s_cnt[1]);
  }
}

__global__ __launch_bounds__(128) void k_final(const float* __restrict__ gsum, const int* __restrict__ gcnt,
                                               void* __restrict__ dout, const int* __restrict__ flag){
  int f32 = *flag;
  int i = blockIdx.x*128 + threadIdx.x;
  if (i < NG*DD){
    float c = (float)gcnt[i>>7];
    if (c < 1.f) c = 1.f;
    float val = gsum[i] / c;
    if (f32) ((float*)dout)[(size_t)NN*DD + i] = val;
    else     ((bf16*)dout)[(size_t)NN*DD + i] = __float2bfloat16(val);
  }
}

extern "C" void kernel_launch(void* const* d_in, const int* in_sizes, int n_in,
                              void* d_out, int out_size, void* d_ws, size_t ws_size,
                              hipStream_t stream){
  const void* x      = d_in[0];
  const int*  ei     = (const int*) d_in[1];
  const int*  batch  = (const int*) d_in[2];
  const void* W0     = d_in[3];
  const void* asrc0  = d_in[4];
  const void* adst0  = d_in[5];
  const void* b0     = d_in[6];
  const void* Ws     = d_in[7];
  const void* asrcs  = d_in[8];
  const void* adsts  = d_in[9];
  const void* bs     = d_in[10];
  const void* lng    = d_in[11];
  const void* lnb    = d_in[12];

  const int* srcs = ei;
  const int* dsts = ei + NE;

  uintptr_t p0 = (uintptr_t)d_ws;
  uintptr_t p = p0;
  auto alloc = [&](size_t bytes)->void* {
    void* r = (void*)p; p += (bytes + 255) & ~(size_t)255; return r;
  };
  int*   csr    = (int*)  alloc((size_t)CSRN*4);        // 7.5 MB fixed-stride CSR
  int*   offs   = (int*)  alloc((size_t)NN*4);
  int*   oend   = (int*)  alloc((size_t)NN*4);
  float* asrc   = (float*)alloc((size_t)NN*NH*4);
  float* adst   = (float*)alloc((size_t)NN*NH*4);
  float* gsum   = (float*)alloc((size_t)NG*DD*4);
  int*   gcnt   = (int*)  alloc(NG*4);
  int*   flag   = (int*)  alloc(256);
  int*   bcur   = (int*)  alloc((size_t)NBUK*4);
  int2*  gstag  = (int2*) alloc((size_t)NBUK*CAPE*8);   // 14.2 MB fixed-stride staging
  bf16*  wt     = (bf16*) alloc((size_t)3*DD*DD*2);     // 96 KB transposed layer weights
  bf16*  hproj  = (bf16*) alloc((size_t)NN*DD*2);       // 25.6 MB
  bf16*  resid  = (bf16*) alloc((size_t)NN*DD*2);       // 25.6 MB residual stream

  const int NB = (NN + 255)/256; // 391

  k_init<<<NB, 256, 0, stream>>>(gsum, gcnt, bcur, (const unsigned int*)x, flag);
  k_bin<<<NBBIN + 3, 256, 0, stream>>>(srcs, dsts, bcur, gstag, Ws, wt, flag);
  k_bucket<<<NBUK, 256, 0, stream>>>(gstag, bcur, csr, offs, oend);

  const int GEMM_B = (NN + 63)/64;  // 1563

  // layer 0
  k_gemm0<<<NN/4, 128, 0, stream>>>(x, W0, asrc0, adst0, hproj, asrc, adst, flag);
  k_agg<8><<<NN/4, 256, 0, stream>>>(hproj, asrc, adst, offs, oend, csr, resid,
                                     b0, 0, lng, lnb, 0, flag, 1);
  // layers 1..3
  for (int l=1; l<4; l++){
    size_t wtoff = (size_t)(l-1)*DD*DD;
    size_t aoff  = (size_t)(l-1)*DD;
    k_gemm_mfma<<<GEMM_B, 256, 0, stream>>>(resid, wt, wtoff,
                                            asrcs, adsts, aoff,
                                            hproj, asrc, adst, flag);
    k_agg<8><<<NN/4, 256, 0, stream>>>(hproj, asrc, adst, offs, oend, csr, resid,
                                       bs, (size_t)(l-1)*DD, lng, lnb, (size_t)l*DD, flag, 0);
  }

  k_pool<<<(NN+63)/64, 256, 0, stream>>>(resid, d_out, batch, gsum, gcnt, flag);
  k_final<<<(NG*DD+127)/128, 128, 0, stream>>>(gsum, gcnt, d_out, flag);
}